// Round 4
// baseline (1169.456 us; speedup 1.0000x reference)
//
#include <hip/hip_runtime.h>

typedef __attribute__((ext_vector_type(8))) short bf16x8;
typedef __attribute__((ext_vector_type(4))) float f32x4;
typedef __attribute__((ext_vector_type(16))) float f32x16;
typedef __attribute__((ext_vector_type(8))) unsigned short u16x8;
typedef __attribute__((ext_vector_type(4))) unsigned u32x4;
typedef unsigned short u16;

#define GLOBAL_AS __attribute__((address_space(1)))
#define LDS_AS __attribute__((address_space(3)))

#define S_ 2048
#define SCALE_ 0.08838834764831845f
#define SMK_ 0.12751741406106783f   // SCALE * log2(e), folded into K at RoPE

static __device__ __forceinline__ u16 f2bf(float f) {
  unsigned u = __builtin_bit_cast(unsigned, f);
  u += 0x7fffu + ((u >> 16) & 1u);
  return (u16)(u >> 16);
}
static __device__ __forceinline__ float bf2f(u16 h) {
  return __builtin_bit_cast(float, ((unsigned)h) << 16);
}
static __device__ __forceinline__ float exp2_raw(float x) {
  float r; asm("v_exp_f32 %0, %1" : "=v"(r) : "v"(x)); return r;
}
static __device__ __forceinline__ unsigned cvtpk(float lo, float hi_) {
  unsigned r; asm("v_cvt_pk_bf16_f32 %0, %1, %2" : "=v"(r) : "v"(lo), "v"(hi_)); return r;
}

// ---------------- fused f32 -> bf16 convert for all 5 tensors ----------------
__global__ __launch_bounds__(256)
void cvt_all(const float* __restrict__ h, const float* __restrict__ wq,
             const float* __restrict__ wk, const float* __restrict__ wv,
             const float* __restrict__ wo, u16* __restrict__ Xbf,
             u16* __restrict__ Wqkv, u16* __restrict__ Wo) {
  const int bid = blockIdx.x;
  const float* src; u16* dst; long base;
  if (bid < 4096)      { src = h;  dst = Xbf;            base = (long)bid * 2048; }
  else if (bid < 6144) { src = wq; dst = Wqkv;           base = (long)(bid - 4096) * 2048; }
  else if (bid < 6656) { src = wk; dst = Wqkv + 4194304; base = (long)(bid - 6144) * 2048; }
  else if (bid < 7168) { src = wv; dst = Wqkv + 5242880; base = (long)(bid - 6656) * 2048; }
  else                 { src = wo; dst = Wo;             base = (long)(bid - 7168) * 2048; }
  const long i = base + (long)threadIdx.x * 8;
  f32x4 a = *(const f32x4*)(src + i);
  f32x4 b = *(const f32x4*)(src + i + 4);
  u16x8 o;
  o[0] = f2bf(a[0]); o[1] = f2bf(a[1]); o[2] = f2bf(a[2]); o[3] = f2bf(a[3]);
  o[4] = f2bf(b[0]); o[5] = f2bf(b[1]); o[6] = f2bf(b[2]); o[7] = f2bf(b[3]);
  *(u16x8*)(dst + i) = o;
}

// ---------------- GEMM: C[m][n] = sum_k A[m][k] * Bw[n][k] ----------------
template <bool BF16OUT>
__global__ __launch_bounds__(256)
void gemm_bt(const u16* __restrict__ A, const u16* __restrict__ Bw,
             void* __restrict__ Cp, int M, int N, int K) {
  __shared__ u16 As[128 * 64];
  __shared__ u16 Bs[128 * 64];
  const int tid = threadIdx.x;
  const int wave = tid >> 6, lane = tid & 63;
  const int fr = lane & 15, fg = lane >> 4;
  const int wm = (wave >> 1) * 64, wn = (wave & 1) * 64;
  const long rowA = (long)blockIdx.y * 128;
  const long rowB = (long)blockIdx.x * 128;

  f32x4 acc[4][4] = {};

  for (int k0 = 0; k0 < K; k0 += 64) {
    __syncthreads();
#pragma unroll
    for (int c = 0; c < 4; ++c) {
      const int base = (wave * 4 + c) * 1024;
      const int off = base + lane * 16;
      const int r = off >> 7;
      const int kc = (off & 127) >> 1;
      __builtin_amdgcn_global_load_lds(
          (GLOBAL_AS void*)(A + (rowA + r) * (long)K + k0 + kc),
          (LDS_AS void*)(As + (base >> 1)), 16, 0, 0);
      __builtin_amdgcn_global_load_lds(
          (GLOBAL_AS void*)(Bw + (rowB + r) * (long)K + k0 + kc),
          (LDS_AS void*)(Bs + (base >> 1)), 16, 0, 0);
    }
    __syncthreads();
#pragma unroll
    for (int ks = 0; ks < 2; ++ks) {
      bf16x8 af[4], bfr[4];
#pragma unroll
      for (int i = 0; i < 4; ++i) {
        af[i]  = *(const bf16x8*)&As[(wm + i * 16 + fr) * 64 + ks * 32 + fg * 8];
        bfr[i] = *(const bf16x8*)&Bs[(wn + i * 16 + fr) * 64 + ks * 32 + fg * 8];
      }
#pragma unroll
      for (int i = 0; i < 4; ++i)
#pragma unroll
        for (int j = 0; j < 4; ++j)
          acc[i][j] = __builtin_amdgcn_mfma_f32_16x16x32_bf16(af[i], bfr[j], acc[i][j], 0, 0, 0);
    }
  }
#pragma unroll
  for (int i = 0; i < 4; ++i)
#pragma unroll
    for (int j = 0; j < 4; ++j)
#pragma unroll
      for (int r = 0; r < 4; ++r) {
        const long row = rowA + wm + i * 16 + fg * 4 + r;
        const long col = rowB + wn + j * 16 + fr;
        if (BF16OUT) ((u16*)Cp)[row * N + col] = f2bf(acc[i][j][r]);
        else         ((float*)Cp)[row * N + col] = acc[i][j][r];
      }
}

// ---------------- RoPE + rearrange; K gets SCALE*log2e folded in ----------------
__global__ __launch_bounds__(256)
void rope_rearrange(const u16* __restrict__ QKV, const float* __restrict__ cosb,
                    const float* __restrict__ sinb, u16* __restrict__ Qr,
                    u16* __restrict__ Kr) {
  const int m = blockIdx.x;            // b*2048 + s
  const int b = m >> 11, s = m & 2047;
  const int t = threadIdx.x;
  const u16* row = QKV + (long)m * 3072;
  const float* cp = cosb + (long)m * 128;
  const float* sp = sinb + (long)m * 128;
#pragma unroll
  for (int i = 0; i < 4; ++i) {        // Q: 16 heads x 64 pairs
    const int idx = i * 256 + t;
    const int h = idx >> 6, d = idx & 63;
    const float x1 = bf2f(row[h * 128 + d]);
    const float x2 = bf2f(row[h * 128 + d + 64]);
    const float c = cp[d], sv = sp[d];
    const long o = ((long)(b * 16 + h) * S_ + s) * 128 + d;
    Qr[o] = f2bf(x1 * c - x2 * sv);
    Qr[o + 64] = f2bf(x2 * c + x1 * sv);
  }
  {                                     // K: 4 heads x 64 pairs (pre-scaled)
    const int h = t >> 6, d = t & 63;
    const float x1 = bf2f(row[2048 + h * 128 + d]);
    const float x2 = bf2f(row[2048 + h * 128 + d + 64]);
    const float c = cp[d], sv = sp[d];
    const long o = ((long)(b * 4 + h) * S_ + s) * 128 + d;
    Kr[o] = f2bf((x1 * c - x2 * sv) * SMK_);
    Kr[o + 64] = f2bf((x2 * c + x1 * sv) * SMK_);
  }
}

// ---------------- V transpose: QKV[b][s][2560+kh*128+d] -> Vt[b][kh][d][s] ----
__global__ __launch_bounds__(256)
void transpose_v(const u16* __restrict__ QKV, u16* __restrict__ Vt) {
  __shared__ u16 t[32][33];
  const int s0 = blockIdx.x * 32, d0 = blockIdx.y * 32;
  const int bk = blockIdx.z;
  const int b = bk >> 2, kh = bk & 3;
  const int tx = threadIdx.x & 31, ty = threadIdx.x >> 5;
  const u16* src = QKV + 2560 + (long)kh * 128;
#pragma unroll
  for (int i = 0; i < 4; ++i) {
    const int sl = ty + i * 8;
    t[sl][tx] = src[(long)(b * S_ + s0 + sl) * 3072 + d0 + tx];
  }
  __syncthreads();
  u16* dst = Vt + (long)(b * 4 + kh) * 128 * S_;
#pragma unroll
  for (int i = 0; i < 4; ++i) {
    const int dl = ty + i * 8;
    dst[(long)(d0 + dl) * S_ + s0 + tx] = t[tx][dl];
  }
}

// ---------------- causal GQA flash attention, swapped-QK 32x32 ----------------
// Persistent 2-warp blocks; dynamic atomic queue over 1024 units (32 q-tiles of
// 64 rows x 32 bh), heavy-first. Per warp: 32 q rows, in-register softmax via
// swapped mfma(K,Q), P->bf16 A-frags via cvt_pk + permlane32_swap.
struct PA2 { bf16x8 a, b; };
static __device__ __forceinline__ PA2 pack_half(const f32x16 s) {
  PA2 out;
#pragma unroll
  for (int ks2 = 0; ks2 < 2; ++ks2) {
    const int rb = ks2 * 8;
    unsigned w0 = cvtpk(s[rb + 0], s[rb + 1]);
    unsigned w1 = cvtpk(s[rb + 2], s[rb + 3]);
    unsigned w2 = cvtpk(s[rb + 4], s[rb + 5]);
    unsigned w3 = cvtpk(s[rb + 6], s[rb + 7]);
    asm("v_permlane32_swap_b32 %0, %1" : "+v"(w0), "+v"(w2));
    asm("v_permlane32_swap_b32 %0, %1" : "+v"(w1), "+v"(w3));
    u32x4 pw; pw[0] = w0; pw[1] = w1; pw[2] = w2; pw[3] = w3;
    if (ks2 == 0) out.a = __builtin_bit_cast(bf16x8, pw);
    else          out.b = __builtin_bit_cast(bf16x8, pw);
  }
  return out;
}

#define NUNITS 1024
__global__ __launch_bounds__(128)
void attn_fwd(const u16* __restrict__ Qr, const u16* __restrict__ Kr,
              const u16* __restrict__ Vt, u16* __restrict__ Att,
              unsigned* __restrict__ ctr) {
  __shared__ u16 Ks[64 * 128];         // [kv][d], chunk^=(kv&7) swizzle
  __shared__ u16 Vs[128 * 64];         // [d][kv], chunk^=(d&7) swizzle
  __shared__ unsigned s_uid;

  const int tid = threadIdx.x, wave = tid >> 6, lane = tid & 63;
  const int l31 = lane & 31, hi = lane >> 5, r7 = lane & 7;

  for (;;) {
    __syncthreads();
    if (tid == 0) s_uid = atomicAdd(ctr, 1u);
    __syncthreads();
    const unsigned uid = s_uid;
    if (uid >= NUNITS) break;

    const int qt = 31 - (int)(uid >> 5);   // heavy-first
    const int bh = uid & 31;
    const int b = bh >> 4, h = bh & 15;
    const int kh = h >> 2;
    const int qwmin = qt * 64 + wave * 32;

    const u16* Qb = Qr + (long)(b * 16 + h) * S_ * 128;
    const u16* Kb = Kr + (long)(b * 4 + kh) * S_ * 128;
    const u16* Vg = Vt + (long)(b * 4 + kh) * 128 * (long)S_;

    bf16x8 qf[8];
    const u16* qrow = Qb + (long)(qwmin + l31) * 128 + hi * 8;
#pragma unroll
    for (int ds = 0; ds < 8; ++ds) qf[ds] = *(const bf16x8*)(qrow + ds * 16);

    f32x16 acc[4] = {};
    float m_run = -1e30f, l_run = 0.f;
    const int qg = qwmin + l31;

    const int ntiles = qt + 1;
    for (int t = 0; t < ntiles; ++t) {
      const int kv0 = t * 64;
      __syncthreads();
#pragma unroll
      for (int c = 0; c < 8; ++c) {
        const int slab = wave * 8 + c;          // 16 slabs x 1KB each
        const int offu = slab * 512 + lane * 8;
        const int kvl = offu >> 7;              // K: 128 u16/row
        const int kc = ((offu >> 3) & 15) ^ (kvl & 7);
        __builtin_amdgcn_global_load_lds(
            (GLOBAL_AS void*)(Kb + (long)(kv0 + kvl) * 128 + kc * 8),
            (LDS_AS void*)(Ks + slab * 512), 16, 0, 0);
        const int dr = offu >> 6;               // V: 64 u16/row
        const int vc = ((offu >> 3) & 7) ^ (dr & 7);
        __builtin_amdgcn_global_load_lds(
            (GLOBAL_AS void*)(Vg + (long)dr * S_ + kv0 + vc * 8),
            (LDS_AS void*)(Vs + slab * 512), 16, 0, 0);
      }
      __syncthreads();

      const bool up_ok = (kv0 + 32) <= (qwmin + 31);  // upper kv-half live?

      // ---- S^T = K Q^T (log2-scaled via K) ----
      f32x16 s0 = {}, s1 = {};
      __builtin_amdgcn_s_setprio(1);
#pragma unroll
      for (int ds = 0; ds < 8; ++ds) {
        const int ch = ((2 * ds + hi) ^ r7) << 3;
        const bf16x8 ka0 = *(const bf16x8*)&Ks[l31 * 128 + ch];
        s0 = __builtin_amdgcn_mfma_f32_32x32x16_bf16(ka0, qf[ds], s0, 0, 0, 0);
      }
      if (up_ok) {
#pragma unroll
        for (int ds = 0; ds < 8; ++ds) {
          const int ch = ((2 * ds + hi) ^ r7) << 3;
          const bf16x8 ka1 = *(const bf16x8*)&Ks[(32 + l31) * 128 + ch];
          s1 = __builtin_amdgcn_mfma_f32_32x32x16_bf16(ka1, qf[ds], s1, 0, 0, 0);
        }
      }
      __builtin_amdgcn_s_setprio(0);

      // ---- causal mask (diagonal tiles only) ----
      if (kv0 + 63 > qwmin) {
#pragma unroll
        for (int r = 0; r < 16; ++r) {
          const int cr = (r & 3) + 8 * (r >> 2) + 4 * hi;
          if (kv0 + cr > qg)      s0[r] = -3.0e38f;
          if (kv0 + 32 + cr > qg) s1[r] = -3.0e38f;
        }
      }

      // ---- in-register online softmax (exp2 domain) ----
      float mx = s0[0];
#pragma unroll
      for (int r = 1; r < 16; ++r) mx = fmaxf(mx, s0[r]);
      if (up_ok) {
#pragma unroll
        for (int r = 0; r < 16; ++r) mx = fmaxf(mx, s1[r]);
      }
      mx = fmaxf(mx, __shfl_xor(mx, 32));

      if (__any(mx > m_run + 8.0f)) {    // defer-max (T13)
        const float mn = fmaxf(m_run, mx);
        const float scq = exp2_raw(m_run - mn);
        m_run = mn; l_run *= scq;
#pragma unroll
        for (int r = 0; r < 16; ++r) {
          const int cr = (r & 3) + 8 * (r >> 2) + 4 * hi;
          const float sr = __shfl(scq, cr);
          acc[0][r] *= sr; acc[1][r] *= sr; acc[2][r] *= sr; acc[3][r] *= sr;
        }
      }

      float rs = 0.f;
#pragma unroll
      for (int r = 0; r < 16; ++r) { s0[r] = exp2_raw(s0[r] - m_run); rs += s0[r]; }
      if (up_ok) {
#pragma unroll
        for (int r = 0; r < 16; ++r) { s1[r] = exp2_raw(s1[r] - m_run); rs += s1[r]; }
      }
      rs += __shfl_xor(rs, 32);
      l_run += rs;

      // ---- P -> bf16 A-fragments + O += P V ----
      bf16x8 pa[4];
      { PA2 p0 = pack_half(s0); pa[0] = p0.a; pa[1] = p0.b; }
      if (up_ok) { PA2 p1 = pack_half(s1); pa[2] = p1.a; pa[3] = p1.b; }

      const int nks = up_ok ? 4 : 2;
      __builtin_amdgcn_s_setprio(1);
#pragma unroll
      for (int nj = 0; nj < 4; ++nj) {
        const int vrow = (nj * 32 + l31) * 64;
        for (int ks = 0; ks < nks; ++ks) {
          const bf16x8 vf = *(const bf16x8*)&Vs[vrow + (((2 * ks + hi) ^ r7) << 3)];
          acc[nj] = __builtin_amdgcn_mfma_f32_32x32x16_bf16(pa[ks], vf, acc[nj], 0, 0, 0);
        }
      }
      __builtin_amdgcn_s_setprio(0);
    }

    // ---- epilogue: normalize (1/l broadcast lane q -> acc lanes), store ----
    const float inv = 1.0f / l_run;
#pragma unroll
    for (int r = 0; r < 16; ++r) {
      const int cr = (r & 3) + 8 * (r >> 2) + 4 * hi;
      const float ir = __shfl(inv, cr);
      const long orow = ((long)b * S_ + qt * 64 + wave * 32 + cr) * 2048 + h * 128 + l31;
      Att[orow]      = f2bf(acc[0][r] * ir);
      Att[orow + 32] = f2bf(acc[1][r] * ir);
      Att[orow + 64] = f2bf(acc[2][r] * ir);
      Att[orow + 96] = f2bf(acc[3][r] * ir);
    }
  }
}

extern "C" void kernel_launch(void* const* d_in, const int* in_sizes, int n_in,
                              void* d_out, int out_size, void* d_ws, size_t ws_size,
                              hipStream_t stream) {
  const float* hidden = (const float*)d_in[0];
  const float* cosb = (const float*)d_in[1];
  const float* sinb = (const float*)d_in[2];
  // d_in[3] = attn_mask: pure causal, implemented analytically
  const float* wq = (const float*)d_in[4];
  const float* wk = (const float*)d_in[5];
  const float* wv = (const float*)d_in[6];
  const float* wo = (const float*)d_in[7];
  float* out = (float*)d_out;

  u16* Xbf  = (u16*)d_ws;                 // 8,388,608
  u16* Wqkv = Xbf + 8388608;              // 6,291,456 (free after gemm1 -> queue ctr)
  u16* Wo   = Wqkv + 6291456;             // 4,194,304
  u16* QKV  = Wo + 4194304;               // 12,582,912
  u16* Qr   = QKV + 12582912;             // 8,388,608
  u16* Kr   = Qr + 8388608;               // 2,097,152
  u16* Vtp  = Kr + 2097152;               // 2,097,152  (V transposed [b][kh][d][s])
  u16* Att  = Xbf;                        // reuse X region after GEMM1
  if (ws_size < (size_t)44040192 * 2) return;

  cvt_all<<<dim3(9216), dim3(256), 0, stream>>>(hidden, wq, wk, wv, wo, Xbf, Wqkv, Wo);
  gemm_bt<true><<<dim3(24, 32), dim3(256), 0, stream>>>(Xbf, Wqkv, (void*)QKV, 4096, 3072, 2048);
  rope_rearrange<<<dim3(4096), dim3(256), 0, stream>>>(QKV, cosb, sinb, Qr, Kr);
  transpose_v<<<dim3(64, 4, 8), dim3(256), 0, stream>>>(QKV, Vtp);
  hipMemsetAsync((void*)Wqkv, 0, 4, stream);           // queue counter := 0
  attn_fwd<<<dim3(768), dim3(128), 0, stream>>>(Qr, Kr, Vtp, Att, (unsigned*)Wqkv);
  gemm_bt<false><<<dim3(16, 32), dim3(256), 0, stream>>>(Att, Wo, (void*)out, 4096, 2048, 2048);
}

// Round 5
// 254.906 us; speedup vs baseline: 4.5878x; 4.5878x over previous
//
#include <hip/hip_runtime.h>

typedef __attribute__((ext_vector_type(8))) short bf16x8;
typedef __attribute__((ext_vector_type(4))) float f32x4;
typedef __attribute__((ext_vector_type(16))) float f32x16;
typedef __attribute__((ext_vector_type(8))) unsigned short u16x8;
typedef __attribute__((ext_vector_type(4))) unsigned u32x4;
typedef unsigned short u16;

#define GLOBAL_AS __attribute__((address_space(1)))
#define LDS_AS __attribute__((address_space(3)))

#define S_ 2048
#define SMK_ 0.12751741406106783f   // SCALE * log2(e), folded into K at RoPE

static __device__ __forceinline__ u16 f2bf(float f) {
  unsigned u = __builtin_bit_cast(unsigned, f);
  u += 0x7fffu + ((u >> 16) & 1u);
  return (u16)(u >> 16);
}
static __device__ __forceinline__ float bf2f(u16 h) {
  return __builtin_bit_cast(float, ((unsigned)h) << 16);
}
static __device__ __forceinline__ float exp2_raw(float x) {
  float r; asm("v_exp_f32 %0, %1" : "=v"(r) : "v"(x)); return r;
}
static __device__ __forceinline__ unsigned cvtpk(float lo, float hi_) {
  unsigned r; asm("v_cvt_pk_bf16_f32 %0, %1, %2" : "=v"(r) : "v"(lo), "v"(hi_)); return r;
}

// ---------------- fused f32 -> bf16 convert for all 5 tensors ----------------
__global__ __launch_bounds__(256)
void cvt_all(const float* __restrict__ h, const float* __restrict__ wq,
             const float* __restrict__ wk, const float* __restrict__ wv,
             const float* __restrict__ wo, u16* __restrict__ Xbf,
             u16* __restrict__ Wqkv, u16* __restrict__ Wo) {
  const int bid = blockIdx.x;
  const float* src; u16* dst; long base;
  if (bid < 4096)      { src = h;  dst = Xbf;            base = (long)bid * 2048; }
  else if (bid < 6144) { src = wq; dst = Wqkv;           base = (long)(bid - 4096) * 2048; }
  else if (bid < 6656) { src = wk; dst = Wqkv + 4194304; base = (long)(bid - 6144) * 2048; }
  else if (bid < 7168) { src = wv; dst = Wqkv + 5242880; base = (long)(bid - 6656) * 2048; }
  else                 { src = wo; dst = Wo;             base = (long)(bid - 7168) * 2048; }
  const long i = base + (long)threadIdx.x * 8;
  f32x4 a = *(const f32x4*)(src + i);
  f32x4 b = *(const f32x4*)(src + i + 4);
  u16x8 o;
  o[0] = f2bf(a[0]); o[1] = f2bf(a[1]); o[2] = f2bf(a[2]); o[3] = f2bf(a[3]);
  o[4] = f2bf(b[0]); o[5] = f2bf(b[1]); o[6] = f2bf(b[2]); o[7] = f2bf(b[3]);
  *(u16x8*)(dst + i) = o;
}

// ---------------- GEMM: C[m][n] = sum_k A[m][k] * Bw[n][k] ----------------
template <bool BF16OUT>
__global__ __launch_bounds__(256)
void gemm_bt(const u16* __restrict__ A, const u16* __restrict__ Bw,
             void* __restrict__ Cp, int M, int N, int K) {
  __shared__ u16 As[128 * 64];
  __shared__ u16 Bs[128 * 64];
  const int tid = threadIdx.x;
  const int wave = tid >> 6, lane = tid & 63;
  const int fr = lane & 15, fg = lane >> 4;
  const int wm = (wave >> 1) * 64, wn = (wave & 1) * 64;
  const long rowA = (long)blockIdx.y * 128;
  const long rowB = (long)blockIdx.x * 128;

  f32x4 acc[4][4] = {};

  for (int k0 = 0; k0 < K; k0 += 64) {
    __syncthreads();
#pragma unroll
    for (int c = 0; c < 4; ++c) {
      const int base = (wave * 4 + c) * 1024;
      const int off = base + lane * 16;
      const int r = off >> 7;
      const int kc = (off & 127) >> 1;
      __builtin_amdgcn_global_load_lds(
          (GLOBAL_AS void*)(A + (rowA + r) * (long)K + k0 + kc),
          (LDS_AS void*)(As + (base >> 1)), 16, 0, 0);
      __builtin_amdgcn_global_load_lds(
          (GLOBAL_AS void*)(Bw + (rowB + r) * (long)K + k0 + kc),
          (LDS_AS void*)(Bs + (base >> 1)), 16, 0, 0);
    }
    __syncthreads();
#pragma unroll
    for (int ks = 0; ks < 2; ++ks) {
      bf16x8 af[4], bfr[4];
#pragma unroll
      for (int i = 0; i < 4; ++i) {
        af[i]  = *(const bf16x8*)&As[(wm + i * 16 + fr) * 64 + ks * 32 + fg * 8];
        bfr[i] = *(const bf16x8*)&Bs[(wn + i * 16 + fr) * 64 + ks * 32 + fg * 8];
      }
#pragma unroll
      for (int i = 0; i < 4; ++i)
#pragma unroll
        for (int j = 0; j < 4; ++j)
          acc[i][j] = __builtin_amdgcn_mfma_f32_16x16x32_bf16(af[i], bfr[j], acc[i][j], 0, 0, 0);
    }
  }
#pragma unroll
  for (int i = 0; i < 4; ++i)
#pragma unroll
    for (int j = 0; j < 4; ++j)
#pragma unroll
      for (int r = 0; r < 4; ++r) {
        const long row = rowA + wm + i * 16 + fg * 4 + r;
        const long col = rowB + wn + j * 16 + fr;
        if (BF16OUT) ((u16*)Cp)[row * N + col] = f2bf(acc[i][j][r]);
        else         ((float*)Cp)[row * N + col] = acc[i][j][r];
      }
}

// ---------------- RoPE + rearrange; K gets SCALE*log2e folded in ----------------
__global__ __launch_bounds__(256)
void rope_rearrange(const u16* __restrict__ QKV, const float* __restrict__ cosb,
                    const float* __restrict__ sinb, u16* __restrict__ Qr,
                    u16* __restrict__ Kr) {
  const int m = blockIdx.x;            // b*2048 + s
  const int b = m >> 11, s = m & 2047;
  const int t = threadIdx.x;
  const u16* row = QKV + (long)m * 3072;
  const float* cp = cosb + (long)m * 128;
  const float* sp = sinb + (long)m * 128;
#pragma unroll
  for (int i = 0; i < 4; ++i) {        // Q: 16 heads x 64 pairs
    const int idx = i * 256 + t;
    const int h = idx >> 6, d = idx & 63;
    const float x1 = bf2f(row[h * 128 + d]);
    const float x2 = bf2f(row[h * 128 + d + 64]);
    const float c = cp[d], sv = sp[d];
    const long o = ((long)(b * 16 + h) * S_ + s) * 128 + d;
    Qr[o] = f2bf(x1 * c - x2 * sv);
    Qr[o + 64] = f2bf(x2 * c + x1 * sv);
  }
  {                                     // K: 4 heads x 64 pairs (pre-scaled)
    const int h = t >> 6, d = t & 63;
    const float x1 = bf2f(row[2048 + h * 128 + d]);
    const float x2 = bf2f(row[2048 + h * 128 + d + 64]);
    const float c = cp[d], sv = sp[d];
    const long o = ((long)(b * 4 + h) * S_ + s) * 128 + d;
    Kr[o] = f2bf((x1 * c - x2 * sv) * SMK_);
    Kr[o + 64] = f2bf((x2 * c + x1 * sv) * SMK_);
  }
}

// ---------------- V transpose: QKV[b][s][2560+kh*128+d] -> Vt[b][kh][d][s] ----
__global__ __launch_bounds__(256)
void transpose_v(const u16* __restrict__ QKV, u16* __restrict__ Vt) {
  __shared__ u16 t[32][33];
  const int s0 = blockIdx.x * 32, d0 = blockIdx.y * 32;
  const int bk = blockIdx.z;
  const int b = bk >> 2, kh = bk & 3;
  const int tx = threadIdx.x & 31, ty = threadIdx.x >> 5;
  const u16* src = QKV + 2560 + (long)kh * 128;
#pragma unroll
  for (int i = 0; i < 4; ++i) {
    const int sl = ty + i * 8;
    t[sl][tx] = src[(long)(b * S_ + s0 + sl) * 3072 + d0 + tx];
  }
  __syncthreads();
  u16* dst = Vt + (long)(b * 4 + kh) * 128 * S_;
#pragma unroll
  for (int i = 0; i < 4; ++i) {
    const int dl = ty + i * 8;
    dst[(long)(d0 + dl) * S_ + s0 + tx] = t[tx][dl];
  }
}

// ---------------- causal GQA flash attention, swapped-QK 32x32 ----------------
// Persistent 2-warp blocks; dynamic atomic queue over 1024 units, heavy-first.
// attn_tile<NH>: per-tile body with ALL register indexing compile-time static
// (rule #20: runtime-indexed ext_vector arrays go to scratch).
struct PA2 { bf16x8 a, b; };
static __device__ __forceinline__ PA2 pack_half(const f32x16 s) {
  PA2 out;
#pragma unroll
  for (int ks2 = 0; ks2 < 2; ++ks2) {
    const int rb = ks2 * 8;
    unsigned w0 = cvtpk(s[rb + 0], s[rb + 1]);
    unsigned w1 = cvtpk(s[rb + 2], s[rb + 3]);
    unsigned w2 = cvtpk(s[rb + 4], s[rb + 5]);
    unsigned w3 = cvtpk(s[rb + 6], s[rb + 7]);
    asm("v_permlane32_swap_b32 %0, %1" : "+v"(w0), "+v"(w2));
    asm("v_permlane32_swap_b32 %0, %1" : "+v"(w1), "+v"(w3));
    u32x4 pw; pw[0] = w0; pw[1] = w1; pw[2] = w2; pw[3] = w3;
    if (ks2 == 0) out.a = __builtin_bit_cast(bf16x8, pw);
    else          out.b = __builtin_bit_cast(bf16x8, pw);
  }
  return out;
}

template <int NH>   // live 32-kv halves in this tile: 2 (full) or 1 (diag, wave0)
static __device__ __forceinline__ void attn_tile(
    const u16* __restrict__ Ks, const u16* __restrict__ Vs,
    const bf16x8 (&qf)[8], f32x16 (&acc)[4], float& m_run, float& l_run,
    const int kv0, const int qwmin, const int qg, const int l31,
    const int hi, const int r7) {
  // ---- S^T = K Q^T (log2-scaled via K) ----
  f32x16 s[NH];
#pragma unroll
  for (int hh = 0; hh < NH; ++hh) s[hh] = (f32x16){};
  __builtin_amdgcn_s_setprio(1);
#pragma unroll
  for (int ds = 0; ds < 8; ++ds) {
    const int ch = ((2 * ds + hi) ^ r7) << 3;
#pragma unroll
    for (int hh = 0; hh < NH; ++hh) {
      const bf16x8 ka = *(const bf16x8*)&Ks[(hh * 32 + l31) * 128 + ch];
      s[hh] = __builtin_amdgcn_mfma_f32_32x32x16_bf16(ka, qf[ds], s[hh], 0, 0, 0);
    }
  }
  __builtin_amdgcn_s_setprio(0);

  // ---- causal mask (diagonal tiles only) ----
  if (kv0 + NH * 32 - 1 > qwmin) {
#pragma unroll
    for (int hh = 0; hh < NH; ++hh)
#pragma unroll
      for (int r = 0; r < 16; ++r) {
        const int cr = (r & 3) + 8 * (r >> 2) + 4 * hi;
        if (kv0 + hh * 32 + cr > qg) s[hh][r] = -3.0e38f;
      }
  }

  // ---- in-register online softmax (exp2 domain) ----
  float mx = s[0][0];
#pragma unroll
  for (int hh = 0; hh < NH; ++hh)
#pragma unroll
    for (int r = 0; r < 16; ++r) mx = fmaxf(mx, s[hh][r]);
  mx = fmaxf(mx, __shfl_xor(mx, 32));

  if (__any(mx > m_run + 8.0f)) {      // defer-max (T13)
    const float mn = fmaxf(m_run, mx);
    const float scq = exp2_raw(m_run - mn);
    m_run = mn; l_run *= scq;
#pragma unroll
    for (int r = 0; r < 16; ++r) {
      const int cr = (r & 3) + 8 * (r >> 2) + 4 * hi;
      const float sr = __shfl(scq, cr);
      acc[0][r] *= sr; acc[1][r] *= sr; acc[2][r] *= sr; acc[3][r] *= sr;
    }
  }

  float rs = 0.f;
#pragma unroll
  for (int hh = 0; hh < NH; ++hh)
#pragma unroll
    for (int r = 0; r < 16; ++r) { s[hh][r] = exp2_raw(s[hh][r] - m_run); rs += s[hh][r]; }
  rs += __shfl_xor(rs, 32);
  l_run += rs;

  // ---- P -> bf16 A-fragments + O += P V (all static indexing) ----
  bf16x8 pa[2 * NH];
#pragma unroll
  for (int hh = 0; hh < NH; ++hh) {
    const PA2 p = pack_half(s[hh]);
    pa[2 * hh] = p.a; pa[2 * hh + 1] = p.b;
  }
  __builtin_amdgcn_s_setprio(1);
#pragma unroll
  for (int nj = 0; nj < 4; ++nj) {
    const int vrow = (nj * 32 + l31) * 64;
#pragma unroll
    for (int ks = 0; ks < 2 * NH; ++ks) {
      const bf16x8 vf = *(const bf16x8*)&Vs[vrow + (((2 * ks + hi) ^ r7) << 3)];
      acc[nj] = __builtin_amdgcn_mfma_f32_32x32x16_bf16(pa[ks], vf, acc[nj], 0, 0, 0);
    }
  }
  __builtin_amdgcn_s_setprio(0);
}

#define NUNITS 1024
__global__ __launch_bounds__(128)
void attn_fwd(const u16* __restrict__ Qr, const u16* __restrict__ Kr,
              const u16* __restrict__ Vt, u16* __restrict__ Att,
              unsigned* __restrict__ ctr) {
  __shared__ u16 Ks[64 * 128];         // [kv][d], chunk^=(kv&7) swizzle
  __shared__ u16 Vs[128 * 64];         // [d][kv], chunk^=(d&7) swizzle
  __shared__ unsigned s_uid;

  const int tid = threadIdx.x, wave = tid >> 6, lane = tid & 63;
  const int l31 = lane & 31, hi = lane >> 5, r7 = lane & 7;

  for (;;) {
    __syncthreads();
    if (tid == 0) s_uid = atomicAdd(ctr, 1u);
    __syncthreads();
    const unsigned uid = s_uid;
    if (uid >= NUNITS) break;

    const int qt = 31 - (int)(uid >> 5);   // heavy-first
    const int bh = uid & 31;
    const int b = bh >> 4, h = bh & 15;
    const int kh = h >> 2;
    const int qwmin = qt * 64 + wave * 32;

    const u16* Qb = Qr + (long)(b * 16 + h) * S_ * 128;
    const u16* Kb = Kr + (long)(b * 4 + kh) * S_ * 128;
    const u16* Vg = Vt + (long)(b * 4 + kh) * 128 * (long)S_;

    bf16x8 qf[8];
    const u16* qrow = Qb + (long)(qwmin + l31) * 128 + hi * 8;
#pragma unroll
    for (int ds = 0; ds < 8; ++ds) qf[ds] = *(const bf16x8*)(qrow + ds * 16);

    f32x16 acc[4] = {};
    float m_run = -1e30f, l_run = 0.f;
    const int qg = qwmin + l31;

    const int ntiles = qt + 1;
    for (int t = 0; t < ntiles; ++t) {
      const int kv0 = t * 64;
      __syncthreads();
#pragma unroll
      for (int c = 0; c < 8; ++c) {
        const int slab = wave * 8 + c;          // 16 slabs x 1KB each
        const int offu = slab * 512 + lane * 8;
        const int kvl = offu >> 7;              // K: 128 u16/row
        const int kc = ((offu >> 3) & 15) ^ (kvl & 7);
        __builtin_amdgcn_global_load_lds(
            (GLOBAL_AS void*)(Kb + (long)(kv0 + kvl) * 128 + kc * 8),
            (LDS_AS void*)(Ks + slab * 512), 16, 0, 0);
        const int dr = offu >> 6;               // V: 64 u16/row
        const int vc = ((offu >> 3) & 7) ^ (dr & 7);
        __builtin_amdgcn_global_load_lds(
            (GLOBAL_AS void*)(Vg + (long)dr * S_ + kv0 + vc * 8),
            (LDS_AS void*)(Vs + slab * 512), 16, 0, 0);
      }
      __syncthreads();

      if (kv0 + 32 <= qwmin + 31)          // full 64-kv tile live
        attn_tile<2>(Ks, Vs, qf, acc, m_run, l_run, kv0, qwmin, qg, l31, hi, r7);
      else if (kv0 <= qwmin + 31)          // diagonal half-tile (wave 0)
        attn_tile<1>(Ks, Vs, qf, acc, m_run, l_run, kv0, qwmin, qg, l31, hi, r7);
    }

    // ---- epilogue: normalize (1/l broadcast lane q -> acc lanes), store ----
    const float inv = 1.0f / l_run;
#pragma unroll
    for (int r = 0; r < 16; ++r) {
      const int cr = (r & 3) + 8 * (r >> 2) + 4 * hi;
      const float ir = __shfl(inv, cr);
      const long orow = ((long)b * S_ + qt * 64 + wave * 32 + cr) * 2048 + h * 128 + l31;
      Att[orow]      = f2bf(acc[0][r] * ir);
      Att[orow + 32] = f2bf(acc[1][r] * ir);
      Att[orow + 64] = f2bf(acc[2][r] * ir);
      Att[orow + 96] = f2bf(acc[3][r] * ir);
    }
  }
}

extern "C" void kernel_launch(void* const* d_in, const int* in_sizes, int n_in,
                              void* d_out, int out_size, void* d_ws, size_t ws_size,
                              hipStream_t stream) {
  const float* hidden = (const float*)d_in[0];
  const float* cosb = (const float*)d_in[1];
  const float* sinb = (const float*)d_in[2];
  // d_in[3] = attn_mask: pure causal, implemented analytically
  const float* wq = (const float*)d_in[4];
  const float* wk = (const float*)d_in[5];
  const float* wv = (const float*)d_in[6];
  const float* wo = (const float*)d_in[7];
  float* out = (float*)d_out;

  u16* Xbf  = (u16*)d_ws;                 // 8,388,608
  u16* Wqkv = Xbf + 8388608;              // 6,291,456 (free after gemm1 -> queue ctr)
  u16* Wo   = Wqkv + 6291456;             // 4,194,304
  u16* QKV  = Wo + 4194304;               // 12,582,912
  u16* Qr   = QKV + 12582912;             // 8,388,608
  u16* Kr   = Qr + 8388608;               // 2,097,152
  u16* Vtp  = Kr + 2097152;               // 2,097,152  (V transposed [b][kh][d][s])
  u16* Att  = Xbf;                        // reuse X region after GEMM1
  if (ws_size < (size_t)44040192 * 2) return;

  cvt_all<<<dim3(9216), dim3(256), 0, stream>>>(hidden, wq, wk, wv, wo, Xbf, Wqkv, Wo);
  gemm_bt<true><<<dim3(24, 32), dim3(256), 0, stream>>>(Xbf, Wqkv, (void*)QKV, 4096, 3072, 2048);
  rope_rearrange<<<dim3(4096), dim3(256), 0, stream>>>(QKV, cosb, sinb, Qr, Kr);
  transpose_v<<<dim3(64, 4, 8), dim3(256), 0, stream>>>(QKV, Vtp);
  hipMemsetAsync((void*)Wqkv, 0, 4, stream);           // queue counter := 0
  attn_fwd<<<dim3(768), dim3(128), 0, stream>>>(Qr, Kr, Vtp, Att, (unsigned*)Wqkv);
  gemm_bt<false><<<dim3(16, 32), dim3(256), 0, stream>>>(Att, Wo, (void*)out, 4096, 2048, 2048);
}

// Round 6
// 224.551 us; speedup vs baseline: 5.2080x; 1.1352x over previous
//
#include <hip/hip_runtime.h>

typedef __attribute__((ext_vector_type(8))) short bf16x8;
typedef __attribute__((ext_vector_type(4))) float f32x4;
typedef __attribute__((ext_vector_type(16))) float f32x16;
typedef __attribute__((ext_vector_type(8))) unsigned short u16x8;
typedef __attribute__((ext_vector_type(4))) unsigned u32x4;
typedef unsigned short u16;

#define GLOBAL_AS __attribute__((address_space(1)))
#define LDS_AS __attribute__((address_space(3)))

#define S_ 2048
#define SMK_ 0.12751741406106783f   // SCALE * log2(e), folded into K at RoPE

static __device__ __forceinline__ u16 f2bf(float f) {
  unsigned u = __builtin_bit_cast(unsigned, f);
  u += 0x7fffu + ((u >> 16) & 1u);
  return (u16)(u >> 16);
}
static __device__ __forceinline__ float bf2f(u16 h) {
  return __builtin_bit_cast(float, ((unsigned)h) << 16);
}
static __device__ __forceinline__ float exp2_raw(float x) {
  float r; asm("v_exp_f32 %0, %1" : "=v"(r) : "v"(x)); return r;
}
static __device__ __forceinline__ unsigned cvtpk(float lo, float hi_) {
  unsigned r; asm("v_cvt_pk_bf16_f32 %0, %1, %2" : "=v"(r) : "v"(lo), "v"(hi_)); return r;
}

// ---------------- fused f32 -> bf16 convert for all 5 tensors ----------------
__global__ __launch_bounds__(256)
void cvt_all(const float* __restrict__ h, const float* __restrict__ wq,
             const float* __restrict__ wk, const float* __restrict__ wv,
             const float* __restrict__ wo, u16* __restrict__ Xbf,
             u16* __restrict__ Wqkv, u16* __restrict__ Wo) {
  const int bid = blockIdx.x;
  const float* src; u16* dst; long base;
  if (bid < 4096)      { src = h;  dst = Xbf;            base = (long)bid * 2048; }
  else if (bid < 6144) { src = wq; dst = Wqkv;           base = (long)(bid - 4096) * 2048; }
  else if (bid < 6656) { src = wk; dst = Wqkv + 4194304; base = (long)(bid - 6144) * 2048; }
  else if (bid < 7168) { src = wv; dst = Wqkv + 5242880; base = (long)(bid - 6656) * 2048; }
  else                 { src = wo; dst = Wo;             base = (long)(bid - 7168) * 2048; }
  const long i = base + (long)threadIdx.x * 8;
  f32x4 a = *(const f32x4*)(src + i);
  f32x4 b = *(const f32x4*)(src + i + 4);
  u16x8 o;
  o[0] = f2bf(a[0]); o[1] = f2bf(a[1]); o[2] = f2bf(a[2]); o[3] = f2bf(a[3]);
  o[4] = f2bf(b[0]); o[5] = f2bf(b[1]); o[6] = f2bf(b[2]); o[7] = f2bf(b[3]);
  *(u16x8*)(dst + i) = o;
}

// ---------------- 256-tile GEMM, ring-4 LDS, counted vmcnt ----------------
// C[m][n] = sum_k A[m][k] * Bw[n][k].  BM=256, BN=NJ*64, BK=32.
// 8 waves (2M x 4N), per-wave out 128 x (BN/4). Ring-4: compute tile t while
// staging tile t+3 (freed buffer => no read/write race; vmcnt never drains).
// LDS chunks XOR-swizzled (c8 ^= row&3) on BOTH stage-source and ds_read.
template <int NJ, bool BF16OUT>
__global__ __launch_bounds__(512, 2)
void gemm256(const u16* __restrict__ A, const u16* __restrict__ Bw,
             void* __restrict__ Cp, int M, int N, int K) {
  __shared__ u16 LA[4][2][4096];        // [buf][half][128 rows * 32 cols]
  __shared__ u16 LB[4][NJ / 2][4096];

  const int tid = threadIdx.x;
  const int wave = tid >> 6, lane = tid & 63;
  const int fr = lane & 15, fg = lane >> 4;
  const int wm = (wave >> 2) * 128;          // 0 / 128
  const int wn = (wave & 3) * (NJ * 16);     // col base within tile
  const long rowA = (long)blockIdx.y * 256;
  const long rowB = (long)blockIdx.x * (NJ * 64);

  // stage mapping: thread tid writes LDS u16 [tid*8 .. +8) of a half-buffer;
  // that physical chunk p=tid&3 at row=tid>>2 holds logical chunk p^(row&3).
  const int srow = tid >> 2;
  const int sc8 = (tid & 3) ^ (srow & 3);
  const int wbase = wave * 512;              // u16, wave-uniform LDS dest base

  const int nt = K >> 5;

  f32x4 acc[8][NJ] = {};

#define STAGE_A(pt)                                                          \
  {                                                                          \
    const int _b = (pt) & 3;                                                 \
    const long _k = (long)(pt) * 32 + sc8 * 8;                               \
    __builtin_amdgcn_global_load_lds(                                        \
        (GLOBAL_AS void*)(A + (rowA + srow) * K + _k),                       \
        (LDS_AS void*)(&LA[_b][0][wbase]), 16, 0, 0);                        \
    __builtin_amdgcn_global_load_lds(                                        \
        (GLOBAL_AS void*)(A + (rowA + 128 + srow) * K + _k),                 \
        (LDS_AS void*)(&LA[_b][1][wbase]), 16, 0, 0);                        \
  }
#define STAGE_B(pt)                                                          \
  {                                                                          \
    const int _b = (pt) & 3;                                                 \
    const long _k = (long)(pt) * 32 + sc8 * 8;                               \
    __builtin_amdgcn_global_load_lds(                                        \
        (GLOBAL_AS void*)(Bw + (rowB + srow) * K + _k),                      \
        (LDS_AS void*)(&LB[_b][0][wbase]), 16, 0, 0);                        \
    if (NJ == 4)                                                             \
      __builtin_amdgcn_global_load_lds(                                      \
          (GLOBAL_AS void*)(Bw + (rowB + 128 + srow) * K + _k),              \
          (LDS_AS void*)(&LB[_b][NJ / 2 - 1][wbase]), 16, 0, 0);             \
  }

  // prologue: stage tiles 0,1,2
  STAGE_A(0); STAGE_B(0);
  STAGE_A(1); STAGE_B(1);
  STAGE_A(2); STAGE_B(2);

  for (int t = 0; t < nt; ++t) {
    const int rem = nt - 1 - t;
    if (NJ == 4) {
      if (rem >= 2)      asm volatile("s_waitcnt vmcnt(8)" ::: "memory");
      else if (rem == 1) asm volatile("s_waitcnt vmcnt(4)" ::: "memory");
      else               asm volatile("s_waitcnt vmcnt(0)" ::: "memory");
    } else {
      if (rem >= 2)      asm volatile("s_waitcnt vmcnt(6)" ::: "memory");
      else if (rem == 1) asm volatile("s_waitcnt vmcnt(3)" ::: "memory");
      else               asm volatile("s_waitcnt vmcnt(0)" ::: "memory");
    }
    __builtin_amdgcn_s_barrier();   // publish tile t to all waves

    const u16* Ah = LA[t & 3][wm >> 7];
    const u16* Bh = LB[t & 3][NJ == 4 ? (wn >> 7) : 0];
    const bool pf = (t + 3) < nt;

    // ---- phase 0: mi 0-3 x all nj ----
    bf16x8 af0[4], bfv[NJ];
#pragma unroll
    for (int mi = 0; mi < 4; ++mi) {
      const int rl = mi * 16 + fr;
      af0[mi] = *(const bf16x8*)&Ah[rl * 32 + ((fg ^ (rl & 3)) << 3)];
    }
#pragma unroll
    for (int nj = 0; nj < NJ; ++nj) {
      const int rb = (wn & 127) + nj * 16 + fr;
      bfv[nj] = *(const bf16x8*)&Bh[rb * 32 + ((fg ^ (rb & 3)) << 3)];
    }
    if (pf) STAGE_A(t + 3);
    __builtin_amdgcn_s_setprio(1);
#pragma unroll
    for (int mi = 0; mi < 4; ++mi)
#pragma unroll
      for (int nj = 0; nj < NJ; ++nj)
        acc[mi][nj] = __builtin_amdgcn_mfma_f32_16x16x32_bf16(af0[mi], bfv[nj], acc[mi][nj], 0, 0, 0);
    __builtin_amdgcn_s_setprio(0);

    // ---- phase 1: mi 4-7 x all nj ----
    bf16x8 af1[4];
#pragma unroll
    for (int mi = 0; mi < 4; ++mi) {
      const int rl = 64 + mi * 16 + fr;
      af1[mi] = *(const bf16x8*)&Ah[rl * 32 + ((fg ^ (rl & 3)) << 3)];
    }
    if (pf) STAGE_B(t + 3);
    __builtin_amdgcn_s_setprio(1);
#pragma unroll
    for (int mi = 0; mi < 4; ++mi)
#pragma unroll
      for (int nj = 0; nj < NJ; ++nj)
        acc[4 + mi][nj] = __builtin_amdgcn_mfma_f32_16x16x32_bf16(af1[mi], bfv[nj], acc[4 + mi][nj], 0, 0, 0);
    __builtin_amdgcn_s_setprio(0);

    __builtin_amdgcn_s_barrier();   // all reads of tile t done before t+4 staging
  }
#undef STAGE_A
#undef STAGE_B

  // ---- epilogue ----
#pragma unroll
  for (int mi = 0; mi < 8; ++mi)
#pragma unroll
    for (int nj = 0; nj < NJ; ++nj)
#pragma unroll
      for (int r = 0; r < 4; ++r) {
        const long row = rowA + wm + mi * 16 + fg * 4 + r;
        const long col = rowB + wn + nj * 16 + fr;
        if (BF16OUT) ((u16*)Cp)[row * N + col] = f2bf(acc[mi][nj][r]);
        else         ((float*)Cp)[row * N + col] = acc[mi][nj][r];
      }
}

// ---------------- RoPE + rearrange; K gets SCALE*log2e folded in ----------------
__global__ __launch_bounds__(256)
void rope_rearrange(const u16* __restrict__ QKV, const float* __restrict__ cosb,
                    const float* __restrict__ sinb, u16* __restrict__ Qr,
                    u16* __restrict__ Kr) {
  const int m = blockIdx.x;            // b*2048 + s
  const int b = m >> 11, s = m & 2047;
  const int t = threadIdx.x;
  const u16* row = QKV + (long)m * 3072;
  const float* cp = cosb + (long)m * 128;
  const float* sp = sinb + (long)m * 128;
#pragma unroll
  for (int i = 0; i < 4; ++i) {        // Q: 16 heads x 64 pairs
    const int idx = i * 256 + t;
    const int h = idx >> 6, d = idx & 63;
    const float x1 = bf2f(row[h * 128 + d]);
    const float x2 = bf2f(row[h * 128 + d + 64]);
    const float c = cp[d], sv = sp[d];
    const long o = ((long)(b * 16 + h) * S_ + s) * 128 + d;
    Qr[o] = f2bf(x1 * c - x2 * sv);
    Qr[o + 64] = f2bf(x2 * c + x1 * sv);
  }
  {                                     // K: 4 heads x 64 pairs (pre-scaled)
    const int h = t >> 6, d = t & 63;
    const float x1 = bf2f(row[2048 + h * 128 + d]);
    const float x2 = bf2f(row[2048 + h * 128 + d + 64]);
    const float c = cp[d], sv = sp[d];
    const long o = ((long)(b * 4 + h) * S_ + s) * 128 + d;
    Kr[o] = f2bf((x1 * c - x2 * sv) * SMK_);
    Kr[o + 64] = f2bf((x2 * c + x1 * sv) * SMK_);
  }
}

// ---------------- V transpose: QKV[b][s][2560+kh*128+d] -> Vt[b][kh][d][s] ----
__global__ __launch_bounds__(256)
void transpose_v(const u16* __restrict__ QKV, u16* __restrict__ Vt) {
  __shared__ u16 t[32][33];
  const int s0 = blockIdx.x * 32, d0 = blockIdx.y * 32;
  const int bk = blockIdx.z;
  const int b = bk >> 2, kh = bk & 3;
  const int tx = threadIdx.x & 31, ty = threadIdx.x >> 5;
  const u16* src = QKV + 2560 + (long)kh * 128;
#pragma unroll
  for (int i = 0; i < 4; ++i) {
    const int sl = ty + i * 8;
    t[sl][tx] = src[(long)(b * S_ + s0 + sl) * 3072 + d0 + tx];
  }
  __syncthreads();
  u16* dst = Vt + (long)(b * 4 + kh) * 128 * S_;
#pragma unroll
  for (int i = 0; i < 4; ++i) {
    const int dl = ty + i * 8;
    dst[(long)(d0 + dl) * S_ + s0 + tx] = t[tx][dl];
  }
}

// ---------------- causal GQA flash attention, swapped-QK 32x32 ----------------
struct PA2 { bf16x8 a, b; };
static __device__ __forceinline__ PA2 pack_half(const f32x16 s) {
  PA2 out;
#pragma unroll
  for (int ks2 = 0; ks2 < 2; ++ks2) {
    const int rb = ks2 * 8;
    unsigned w0 = cvtpk(s[rb + 0], s[rb + 1]);
    unsigned w1 = cvtpk(s[rb + 2], s[rb + 3]);
    unsigned w2 = cvtpk(s[rb + 4], s[rb + 5]);
    unsigned w3 = cvtpk(s[rb + 6], s[rb + 7]);
    asm("v_permlane32_swap_b32 %0, %1" : "+v"(w0), "+v"(w2));
    asm("v_permlane32_swap_b32 %0, %1" : "+v"(w1), "+v"(w3));
    u32x4 pw; pw[0] = w0; pw[1] = w1; pw[2] = w2; pw[3] = w3;
    if (ks2 == 0) out.a = __builtin_bit_cast(bf16x8, pw);
    else          out.b = __builtin_bit_cast(bf16x8, pw);
  }
  return out;
}

template <int NH>   // live 32-kv halves in this tile: 2 (full) or 1 (diag, wave0)
static __device__ __forceinline__ void attn_tile(
    const u16* __restrict__ Ks, const u16* __restrict__ Vs,
    const bf16x8 (&qf)[8], f32x16 (&acc)[4], float& m_run, float& l_run,
    const int kv0, const int qwmin, const int qg, const int l31,
    const int hi, const int r7) {
  f32x16 s[NH];
#pragma unroll
  for (int hh = 0; hh < NH; ++hh) s[hh] = (f32x16){};
  __builtin_amdgcn_s_setprio(1);
#pragma unroll
  for (int ds = 0; ds < 8; ++ds) {
    const int ch = ((2 * ds + hi) ^ r7) << 3;
#pragma unroll
    for (int hh = 0; hh < NH; ++hh) {
      const bf16x8 ka = *(const bf16x8*)&Ks[(hh * 32 + l31) * 128 + ch];
      s[hh] = __builtin_amdgcn_mfma_f32_32x32x16_bf16(ka, qf[ds], s[hh], 0, 0, 0);
    }
  }
  __builtin_amdgcn_s_setprio(0);

  if (kv0 + NH * 32 - 1 > qwmin) {
#pragma unroll
    for (int hh = 0; hh < NH; ++hh)
#pragma unroll
      for (int r = 0; r < 16; ++r) {
        const int cr = (r & 3) + 8 * (r >> 2) + 4 * hi;
        if (kv0 + hh * 32 + cr > qg) s[hh][r] = -3.0e38f;
      }
  }

  float mx = s[0][0];
#pragma unroll
  for (int hh = 0; hh < NH; ++hh)
#pragma unroll
    for (int r = 0; r < 16; ++r) mx = fmaxf(mx, s[hh][r]);
  mx = fmaxf(mx, __shfl_xor(mx, 32));

  if (__any(mx > m_run + 8.0f)) {      // defer-max (T13)
    const float mn = fmaxf(m_run, mx);
    const float scq = exp2_raw(m_run - mn);
    m_run = mn; l_run *= scq;
#pragma unroll
    for (int r = 0; r < 16; ++r) {
      const int cr = (r & 3) + 8 * (r >> 2) + 4 * hi;
      const float sr = __shfl(scq, cr);
      acc[0][r] *= sr; acc[1][r] *= sr; acc[2][r] *= sr; acc[3][r] *= sr;
    }
  }

  float rs = 0.f;
#pragma unroll
  for (int hh = 0; hh < NH; ++hh)
#pragma unroll
    for (int r = 0; r < 16; ++r) { s[hh][r] = exp2_raw(s[hh][r] - m_run); rs += s[hh][r]; }
  rs += __shfl_xor(rs, 32);
  l_run += rs;

  bf16x8 pa[2 * NH];
#pragma unroll
  for (int hh = 0; hh < NH; ++hh) {
    const PA2 p = pack_half(s[hh]);
    pa[2 * hh] = p.a; pa[2 * hh + 1] = p.b;
  }
  __builtin_amdgcn_s_setprio(1);
#pragma unroll
  for (int nj = 0; nj < 4; ++nj) {
    const int vrow = (nj * 32 + l31) * 64;
#pragma unroll
    for (int ks = 0; ks < 2 * NH; ++ks) {
      const bf16x8 vf = *(const bf16x8*)&Vs[vrow + (((2 * ks + hi) ^ r7) << 3)];
      acc[nj] = __builtin_amdgcn_mfma_f32_32x32x16_bf16(pa[ks], vf, acc[nj], 0, 0, 0);
    }
  }
  __builtin_amdgcn_s_setprio(0);
}

#define NUNITS 1024
__global__ __launch_bounds__(128)
void attn_fwd(const u16* __restrict__ Qr, const u16* __restrict__ Kr,
              const u16* __restrict__ Vt, u16* __restrict__ Att,
              unsigned* __restrict__ ctr) {
  __shared__ u16 Ks[64 * 128];         // [kv][d], chunk^=(kv&7) swizzle
  __shared__ u16 Vs[128 * 64];         // [d][kv], chunk^=(d&7) swizzle
  __shared__ unsigned s_uid;

  const int tid = threadIdx.x, wave = tid >> 6, lane = tid & 63;
  const int l31 = lane & 31, hi = lane >> 5, r7 = lane & 7;

  for (;;) {
    __syncthreads();
    if (tid == 0) s_uid = atomicAdd(ctr, 1u);
    __syncthreads();
    const unsigned uid = s_uid;
    if (uid >= NUNITS) break;

    const int qt = 31 - (int)(uid >> 5);   // heavy-first
    const int bh = uid & 31;
    const int b = bh >> 4, h = bh & 15;
    const int kh = h >> 2;
    const int qwmin = qt * 64 + wave * 32;

    const u16* Qb = Qr + (long)(b * 16 + h) * S_ * 128;
    const u16* Kb = Kr + (long)(b * 4 + kh) * S_ * 128;
    const u16* Vg = Vt + (long)(b * 4 + kh) * 128 * (long)S_;

    bf16x8 qf[8];
    const u16* qrow = Qb + (long)(qwmin + l31) * 128 + hi * 8;
#pragma unroll
    for (int ds = 0; ds < 8; ++ds) qf[ds] = *(const bf16x8*)(qrow + ds * 16);

    f32x16 acc[4] = {};
    float m_run = -1e30f, l_run = 0.f;
    const int qg = qwmin + l31;

    const int ntiles = qt + 1;
    for (int t = 0; t < ntiles; ++t) {
      const int kv0 = t * 64;
      __syncthreads();
#pragma unroll
      for (int c = 0; c < 8; ++c) {
        const int slab = wave * 8 + c;          // 16 slabs x 1KB each
        const int offu = slab * 512 + lane * 8;
        const int kvl = offu >> 7;              // K: 128 u16/row
        const int kc = ((offu >> 3) & 15) ^ (kvl & 7);
        __builtin_amdgcn_global_load_lds(
            (GLOBAL_AS void*)(Kb + (long)(kv0 + kvl) * 128 + kc * 8),
            (LDS_AS void*)(Ks + slab * 512), 16, 0, 0);
        const int dr = offu >> 6;               // V: 64 u16/row
        const int vc = ((offu >> 3) & 7) ^ (dr & 7);
        __builtin_amdgcn_global_load_lds(
            (GLOBAL_AS void*)(Vg + (long)dr * S_ + kv0 + vc * 8),
            (LDS_AS void*)(Vs + slab * 512), 16, 0, 0);
      }
      __syncthreads();

      if (kv0 + 32 <= qwmin + 31)
        attn_tile<2>(Ks, Vs, qf, acc, m_run, l_run, kv0, qwmin, qg, l31, hi, r7);
      else if (kv0 <= qwmin + 31)
        attn_tile<1>(Ks, Vs, qf, acc, m_run, l_run, kv0, qwmin, qg, l31, hi, r7);
    }

    const float inv = 1.0f / l_run;
#pragma unroll
    for (int r = 0; r < 16; ++r) {
      const int cr = (r & 3) + 8 * (r >> 2) + 4 * hi;
      const float ir = __shfl(inv, cr);
      const long orow = ((long)b * S_ + qt * 64 + wave * 32 + cr) * 2048 + h * 128 + l31;
      Att[orow]      = f2bf(acc[0][r] * ir);
      Att[orow + 32] = f2bf(acc[1][r] * ir);
      Att[orow + 64] = f2bf(acc[2][r] * ir);
      Att[orow + 96] = f2bf(acc[3][r] * ir);
    }
  }
}

extern "C" void kernel_launch(void* const* d_in, const int* in_sizes, int n_in,
                              void* d_out, int out_size, void* d_ws, size_t ws_size,
                              hipStream_t stream) {
  const float* hidden = (const float*)d_in[0];
  const float* cosb = (const float*)d_in[1];
  const float* sinb = (const float*)d_in[2];
  // d_in[3] = attn_mask: pure causal, implemented analytically
  const float* wq = (const float*)d_in[4];
  const float* wk = (const float*)d_in[5];
  const float* wv = (const float*)d_in[6];
  const float* wo = (const float*)d_in[7];
  float* out = (float*)d_out;

  u16* Xbf  = (u16*)d_ws;                 // 8,388,608
  u16* Wqkv = Xbf + 8388608;              // 6,291,456 (free after gemm1 -> queue ctr)
  u16* Wo   = Wqkv + 6291456;             // 4,194,304
  u16* QKV  = Wo + 4194304;               // 12,582,912
  u16* Qr   = QKV + 12582912;             // 8,388,608
  u16* Kr   = Qr + 8388608;               // 2,097,152
  u16* Vtp  = Kr + 2097152;               // 2,097,152  (V transposed [b][kh][d][s])
  u16* Att  = Xbf;                        // reuse X region after GEMM1
  if (ws_size < (size_t)44040192 * 2) return;

  cvt_all<<<dim3(9216), dim3(256), 0, stream>>>(hidden, wq, wk, wv, wo, Xbf, Wqkv, Wo);
  gemm256<4, true><<<dim3(12, 16), dim3(512), 0, stream>>>(Xbf, Wqkv, (void*)QKV, 4096, 3072, 2048);
  rope_rearrange<<<dim3(4096), dim3(256), 0, stream>>>(QKV, cosb, sinb, Qr, Kr);
  transpose_v<<<dim3(64, 4, 8), dim3(256), 0, stream>>>(QKV, Vtp);
  hipMemsetAsync((void*)Wqkv, 0, 4, stream);           // queue counter := 0
  attn_fwd<<<dim3(768), dim3(128), 0, stream>>>(Qr, Kr, Vtp, Att, (unsigned*)Wqkv);
  gemm256<2, false><<<dim3(16, 16), dim3(512), 0, stream>>>(Att, Wo, (void*)out, 4096, 2048, 2048);
}